// Round 1
// baseline (107.413 us; speedup 1.0000x reference)
//
#include <hip/hip_runtime.h>
#include <stdint.h>

#define N_PTS 32768
#define K_CB  1024
#define D_DIM 64
#define PITCH 68   // 272B rows: 16B-aligned, bank starts spread (4 mod 32 per row)

// ws layout (bytes):
//   [0,       131072): token[32768] int32
//   [131072,  133120): lossPartial[512] float
//   [133120,  137216): minDist[1024] uint (positive-float bits)
//   [137216,  141312): active[1024] int32
//   [141312,  145408): c2[1024] float

__global__ __launch_bounds__(256) void vq_k0_init(const float* __restrict__ cb,
                                                  unsigned* __restrict__ minDist,
                                                  int* __restrict__ active,
                                                  float* __restrict__ c2) {
    int k = blockIdx.x * 256 + threadIdx.x;
    if (k < K_CB) {
        minDist[k] = 0x7F800000u;   // +inf bits
        active[k]  = 0;
        const float4* row = reinterpret_cast<const float4*>(cb + k * D_DIM);
        float s = 0.f;
#pragma unroll
        for (int q = 0; q < 16; ++q) {
            float4 v = row[q];
            s = fmaf(v.x, v.x, s); s = fmaf(v.y, v.y, s);
            s = fmaf(v.z, v.z, s); s = fmaf(v.w, v.w, s);
        }
        c2[k] = s;
    }
}

__global__ __launch_bounds__(256) void vq_k1_main(const float* __restrict__ x,
                                                  const float* __restrict__ cb,
                                                  const float* __restrict__ c2g,
                                                  unsigned* __restrict__ minDist,
                                                  int* __restrict__ active,
                                                  int* __restrict__ token,
                                                  float* __restrict__ lossPartial) {
    __shared__ float As[64 * PITCH];
    __shared__ float Bs[64 * PITCH];
    __shared__ float x2s[64];
    __shared__ float ldsmin[4][64];
    __shared__ float wsum[16];

    const int tid = threadIdx.x;
    const int tx = tid & 15;        // code lane 0..15
    const int ty = tid >> 4;        // point lane 0..15
    const int p0 = blockIdx.x * 64;

    // ---- stage A tile (64 points x 64 d), coalesced 256B segments ----
#pragma unroll
    for (int r = 0; r < 4; ++r) {
        int pl = r * 16 + (tid >> 4);
        int d4 = tid & 15;
        float4 v = reinterpret_cast<const float4*>(x)[(size_t)(p0 + pl) * 16 + d4];
        *reinterpret_cast<float4*>(&As[pl * PITCH + d4 * 4]) = v;
    }
    __syncthreads();

    // x2 per point, sequential-over-d fma chain (matches reference decomposition)
    if (tid < 64) {
        float s = 0.f;
        for (int d = 0; d < 64; ++d) {
            float a = As[tid * PITCH + d];
            s = fmaf(a, a, s);
        }
        x2s[tid] = s;
    }
    __syncthreads();

    float x2r[4];
#pragma unroll
    for (int i = 0; i < 4; ++i) x2r[i] = x2s[ty + 16 * i];

    unsigned long long best[4];
#pragma unroll
    for (int i = 0; i < 4; ++i) best[i] = 0xFFFFFFFFFFFFFFFFull;

    // ---- loop over 16 codebook tiles of 64 codes ----
    for (int t = 0; t < 16; ++t) {
        const int k0 = t * 64;
        __syncthreads();   // Bs / ldsmin reuse guard
#pragma unroll
        for (int r = 0; r < 4; ++r) {
            int cl = r * 16 + (tid >> 4);
            int d4 = tid & 15;
            float4 v = reinterpret_cast<const float4*>(cb)[(size_t)(k0 + cl) * 16 + d4];
            *reinterpret_cast<float4*>(&Bs[cl * PITCH + d4 * 4]) = v;
        }
        __syncthreads();

        float acc[4][4] = {};
#pragma unroll
        for (int d4 = 0; d4 < 16; ++d4) {
            float4 a[4], b[4];
#pragma unroll
            for (int i = 0; i < 4; ++i)
                a[i] = *reinterpret_cast<const float4*>(&As[(ty + 16 * i) * PITCH + d4 * 4]);
#pragma unroll
            for (int j = 0; j < 4; ++j)
                b[j] = *reinterpret_cast<const float4*>(&Bs[(tx + 16 * j) * PITCH + d4 * 4]);
#pragma unroll
            for (int i = 0; i < 4; ++i)
#pragma unroll
                for (int j = 0; j < 4; ++j) {
                    acc[i][j] = fmaf(a[i].x, b[j].x, acc[i][j]);
                    acc[i][j] = fmaf(a[i].y, b[j].y, acc[i][j]);
                    acc[i][j] = fmaf(a[i].z, b[j].z, acc[i][j]);
                    acc[i][j] = fmaf(a[i].w, b[j].w, acc[i][j]);
                }
        }

        // epilogue: dist = (x2 - 2*xc) + c2  (exact reference association)
        float c2r[4];
#pragma unroll
        for (int j = 0; j < 4; ++j) c2r[j] = c2g[k0 + tx + 16 * j];

        float colmin[4];
#pragma unroll
        for (int j = 0; j < 4; ++j) {
            float cm = 3.4e38f;
            const unsigned kidx = (unsigned)(k0 + tx + 16 * j);
#pragma unroll
            for (int i = 0; i < 4; ++i) {
                float dist = (x2r[i] - 2.0f * acc[i][j]) + c2r[j];
                unsigned long long pk =
                    ((unsigned long long)__float_as_uint(dist) << 32) | kidx;
                if (pk < best[i]) best[i] = pk;   // ties -> lower k (np first-occurrence)
                cm = fminf(cm, dist);
            }
            colmin[j] = cm;
        }
        // per-code min across the wave's 16 points (ty bits = lane 16,32)
#pragma unroll
        for (int j = 0; j < 4; ++j) {
            colmin[j] = fminf(colmin[j], __shfl_xor(colmin[j], 16));
            colmin[j] = fminf(colmin[j], __shfl_xor(colmin[j], 32));
        }
        int lane = tid & 63;
        int wv = tid >> 6;
        if (lane < 16) {
#pragma unroll
            for (int j = 0; j < 4; ++j) ldsmin[wv][lane + 16 * j] = colmin[j];
        }
        __syncthreads();
        if (tid < 64) {
            float m = fminf(fminf(ldsmin[0][tid], ldsmin[1][tid]),
                            fminf(ldsmin[2][tid], ldsmin[3][tid]));
            atomicMin(minDist + (k0 + tid), __float_as_uint(m));  // positive floats: bit-order == value-order
        }
    }

    // ---- final per-point argmin across tx lanes ----
#pragma unroll
    for (int i = 0; i < 4; ++i) {
#pragma unroll
        for (int m = 1; m < 16; m <<= 1) {
            unsigned long long o = __shfl_xor(best[i], m);
            if (o < best[i]) best[i] = o;
        }
    }
    if (tx == 0) {
        float s = 0.f;
#pragma unroll
        for (int i = 0; i < 4; ++i) {
            int p = p0 + ty + 16 * i;
            unsigned kbest = (unsigned)(best[i] & 0xFFFFFFFFu);
            float dbest = __uint_as_float((unsigned)(best[i] >> 32));
            token[p] = (int)kbest;
            atomicAdd(&active[kbest], 1);
            s += dbest;
        }
        wsum[ty] = s;
    }
    __syncthreads();
    if (tid == 0) {
        float s = 0.f;
#pragma unroll
        for (int q = 0; q < 16; ++q) s += wsum[q];
        lossPartial[blockIdx.x] = s;
    }
}

// straight-through output: out = x + (emb - x), elementwise in fp32
__global__ __launch_bounds__(256) void vq_k2_out(const float* __restrict__ x,
                                                 const float* __restrict__ cb,
                                                 const int* __restrict__ token,
                                                 float* __restrict__ out) {
    int g = blockIdx.x * 256 + threadIdx.x;   // float4 index, 524288 total
    int p = g >> 4, q = g & 15;
    int tok = token[p];
    float4 xv = reinterpret_cast<const float4*>(x)[g];
    float4 cv = reinterpret_cast<const float4*>(cb)[tok * 16 + q];
    float4 o;
    o.x = xv.x + (cv.x - xv.x);
    o.y = xv.y + (cv.y - xv.y);
    o.z = xv.z + (cv.z - xv.z);
    o.w = xv.w + (cv.w - xv.w);
    reinterpret_cast<float4*>(out)[g] = o;
}

__global__ __launch_bounds__(1024) void vq_k3_final(const unsigned* __restrict__ minDist,
                                                    const int* __restrict__ active,
                                                    const float* __restrict__ lossPartial,
                                                    float* __restrict__ out_loss) {
    __shared__ double red[1024];
    __shared__ double entS;
    int t = threadIdx.x;

    red[t] = (active[t] == 0) ? (double)__uint_as_float(minDist[t]) : 0.0;
    __syncthreads();
    for (int s = 512; s > 0; s >>= 1) {
        if (t < s) red[t] += red[t + s];
        __syncthreads();
    }
    if (t == 0) entS = red[0];
    __syncthreads();

    red[t] = (t < 512) ? (double)lossPartial[t] : 0.0;
    __syncthreads();
    for (int s = 512; s > 0; s >>= 1) {
        if (t < s) red[t] += red[t + s];
        __syncthreads();
    }
    if (t == 0) {
        double mean_sq = red[0] / (double)((long long)N_PTS * D_DIM);
        double total = 1.25 * mean_sq + 0.01 * (entS / (double)K_CB);
        out_loss[0] = (float)total;
    }
}

extern "C" void kernel_launch(void* const* d_in, const int* in_sizes, int n_in,
                              void* d_out, int out_size, void* d_ws, size_t ws_size,
                              hipStream_t stream) {
    const float* x  = (const float*)d_in[0];
    const float* cb = (const float*)d_in[1];
    float* out = (float*)d_out;
    char* ws = (char*)d_ws;

    int*      token       = (int*)(ws);
    float*    lossPartial = (float*)(ws + 131072);
    unsigned* minDist     = (unsigned*)(ws + 133120);
    int*      active      = (int*)(ws + 137216);
    float*    c2          = (float*)(ws + 141312);

    vq_k0_init <<<4,    256, 0, stream>>>(cb, minDist, active, c2);
    vq_k1_main <<<512,  256, 0, stream>>>(x, cb, c2, minDist, active, token, lossPartial);
    vq_k2_out  <<<2048, 256, 0, stream>>>(x, cb, token, out);
    vq_k3_final<<<1,   1024, 0, stream>>>(minDist, active, lossPartial, out + 2097152);
}

// Round 2
// 63.749 us; speedup vs baseline: 1.6849x; 1.6849x over previous
//
#include <hip/hip_runtime.h>
#include <stdint.h>

typedef float f32x4 __attribute__((ext_vector_type(4)));
typedef short bf16x8 __attribute__((ext_vector_type(8)));
typedef unsigned long long u64t;

#define N_PTS 32768
#define K_CB  1024
#define D_DIM 64
#define QCAP  2048
#define EPS   0.125f
#define NSHARD 16

// ws layout (bytes):
#define WS_TOKEN 0        // int[32768]           131072
#define WS_LOSSP 131072   // float[512]           2048
#define WS_MIND  133120   // u32[1024]            4096
#define WS_ACT   137216   // int[1024]            4096
#define WS_C2    141312   // float[1024]          4096
#define WS_PCB   145408   // ushort[65536] bf16   131072 (frag-linear permuted codebook)
#define WS_SHARD 276480   // u32[16*1024]         65536

__device__ __forceinline__ unsigned short f2bf(float f) {
    unsigned u = __float_as_uint(f);
    unsigned r = u + 0x7FFFu + ((u >> 16) & 1u);   // RNE
    return (unsigned short)(r >> 16);
}

__device__ __forceinline__ void gld16(const void* g, void* l) {
    __builtin_amdgcn_global_load_lds(
        (const __attribute__((address_space(1))) unsigned int*)g,
        (__attribute__((address_space(3))) unsigned int*)l,
        16, 0, 0);
}

// k0: init shards/active, c2, and permuted bf16 codebook (frag-linear for MFMA B-operand)
__global__ __launch_bounds__(256) void vq_k0(const float* __restrict__ cb,
                                             unsigned* __restrict__ shard,
                                             int* __restrict__ active,
                                             float* __restrict__ c2,
                                             unsigned short* __restrict__ pcb) {
    int g = blockIdx.x * 256 + threadIdx.x;   // grid 64 -> 16384 threads
    shard[g] = 0x7F800000u;
    if (g < K_CB) {
        active[g] = 0;
        const float4* row = (const float4*)(cb + g * 64);
        float s = 0.f;
#pragma unroll
        for (int q = 0; q < 16; ++q) {
            float4 v = row[q];
            s = fmaf(v.x, v.x, s); s = fmaf(v.y, v.y, s);
            s = fmaf(v.z, v.z, s); s = fmaf(v.w, v.w, s);
        }
        c2[g] = s;
    }
    if (g < 8192) {   // unit = (code c, 8-elem d-chunk u)
        int c = g >> 3, u = g & 7;
        const float4* row = (const float4*)(cb + c * 64);
        float4 v0 = row[u * 2], v1 = row[u * 2 + 1];
        bf16x8 o;
        o[0] = (short)f2bf(v0.x); o[1] = (short)f2bf(v0.y);
        o[2] = (short)f2bf(v0.z); o[3] = (short)f2bf(v0.w);
        o[4] = (short)f2bf(v1.x); o[5] = (short)f2bf(v1.y);
        o[6] = (short)f2bf(v1.z); o[7] = (short)f2bf(v1.w);
        int frag  = (c >> 4) * 2 + (u >> 2);        // (ctile16, kk)
        int lane8 = (c & 15) + 16 * (u & 3);        // B-frag lane: col=lane&15, k16=(lane>>4)
        *(bf16x8*)&pcb[frag * 512 + lane8 * 8] = o;
    }
}

// k1: 512 blocks x 64 points. bf16-MFMA approx dists + margin-collect + fp32 rescore.
__global__ __launch_bounds__(256, 2) void vq_k1(const float* __restrict__ x,
                                                const float* __restrict__ cb,
                                                const float* __restrict__ c2g,
                                                const unsigned short* __restrict__ pcb,
                                                unsigned* __restrict__ shard,
                                                int* __restrict__ active,
                                                int* __restrict__ token,
                                                float* __restrict__ lossPartial) {
    __shared__ __align__(16) unsigned short cbF[16384];  // 32KB: 256-code tile, frag-linear
    __shared__ __align__(16) unsigned short aF[4096];    // 8KB: 64x64 x-bf16, frag-linear
    __shared__ float    c2s[1024];
    __shared__ float    x2s[64];
    __shared__ unsigned mrun[64];
    __shared__ float    mcode[1024];
    __shared__ u64t     best[64];
    __shared__ unsigned queue[QCAP];
    __shared__ unsigned qcount;
    __shared__ float    dsum[64];

    const int tid  = threadIdx.x;
    const int lane = tid & 63;
    const int w    = tid >> 6;
    const int p0   = blockIdx.x * 64;

    if (tid < 64) { mrun[tid] = 0x7F800000u; best[tid] = ~0ull; }
    if (tid == 0) qcount = 0;
#pragma unroll
    for (int q = 0; q < 4; ++q) c2s[tid + q * 256] = c2g[tid + q * 256];

    // stage x -> bf16 frag-linear LDS (2 units of 8 floats per thread)
#pragma unroll
    for (int q = 0; q < 2; ++q) {
        int unit = tid * 2 + q;
        int r = unit >> 3, u = unit & 7;
        const float4* row = (const float4*)(x + (size_t)(p0 + r) * 64);
        float4 v0 = row[u * 2], v1 = row[u * 2 + 1];
        bf16x8 o;
        o[0] = (short)f2bf(v0.x); o[1] = (short)f2bf(v0.y);
        o[2] = (short)f2bf(v0.z); o[3] = (short)f2bf(v0.w);
        o[4] = (short)f2bf(v1.x); o[5] = (short)f2bf(v1.y);
        o[6] = (short)f2bf(v1.z); o[7] = (short)f2bf(v1.w);
        int frag  = (r >> 4) * 2 + (u >> 2);
        int lane8 = (r & 15) + 16 * (u & 3);
        *(bf16x8*)&aF[frag * 512 + lane8 * 8] = o;
    }
    // exact x2 (sequential fma, same association as round-1 verified formula)
    if (tid < 64) {
        const float* xr = x + (size_t)(p0 + tid) * 64;
        float s = 0.f;
#pragma unroll
        for (int d = 0; d < 64; ++d) s = fmaf(xr[d], xr[d], s);
        x2s[tid] = s;
    }
    __syncthreads();

    bf16x8 a[4][2];
#pragma unroll
    for (int rf = 0; rf < 4; ++rf)
#pragma unroll
        for (int kk = 0; kk < 2; ++kk)
            a[rf][kk] = *(const bf16x8*)&aF[(rf * 2 + kk) * 512 + lane * 8];

    float x2r[4][4];
#pragma unroll
    for (int rf = 0; rf < 4; ++rf)
#pragma unroll
        for (int i = 0; i < 4; ++i)
            x2r[rf][i] = x2s[rf * 16 + (lane >> 4) * 4 + i];

    const char* srcBase = ((const char*)pcb) + (size_t)(w * 8192 + lane * 16);
    char*       dstBase = ((char*)cbF) + (w * 8192 + lane * 16);

    for (int t = 0; t < 4; ++t) {
        __syncthreads();   // prior tile's LDS reads complete before overwrite
#pragma unroll
        for (int it = 0; it < 8; ++it)
            gld16(srcBase + t * 32768 + it * 1024, dstBase + it * 1024);
        __syncthreads();   // drains vmcnt -> tile resident

        f32x4 acc[4][4];
#pragma unroll
        for (int rf = 0; rf < 4; ++rf)
#pragma unroll
            for (int cf = 0; cf < 4; ++cf)
                acc[rf][cf] = (f32x4){0.f, 0.f, 0.f, 0.f};

#pragma unroll
        for (int cf = 0; cf < 4; ++cf)
#pragma unroll
            for (int kk = 0; kk < 2; ++kk) {
                bf16x8 b = *(const bf16x8*)&cbF[((w * 4 + cf) * 2 + kk) * 512 + lane * 8];
#pragma unroll
                for (int rf = 0; rf < 4; ++rf)
                    acc[rf][cf] = __builtin_amdgcn_mfma_f32_16x16x32_bf16(
                        a[rf][kk], b, acc[rf][cf], 0, 0, 0);
            }

        // epilogue A: approx dist, per-point & per-code running mins
        float c2r[4];
#pragma unroll
        for (int cf = 0; cf < 4; ++cf)
            c2r[cf] = c2s[t * 256 + w * 64 + cf * 16 + (lane & 15)];
#pragma unroll
        for (int rf = 0; rf < 4; ++rf)
#pragma unroll
            for (int cf = 0; cf < 4; ++cf)
#pragma unroll
                for (int i = 0; i < 4; ++i)
                    acc[rf][cf][i] = (x2r[rf][i] - 2.f * acc[rf][cf][i]) + c2r[cf];

#pragma unroll
        for (int rf = 0; rf < 4; ++rf)
#pragma unroll
            for (int i = 0; i < 4; ++i) {
                float mp = fminf(fminf(acc[rf][0][i], acc[rf][1][i]),
                                 fminf(acc[rf][2][i], acc[rf][3][i]));
                mp = fminf(mp, __shfl_xor(mp, 1));
                mp = fminf(mp, __shfl_xor(mp, 2));
                mp = fminf(mp, __shfl_xor(mp, 4));
                mp = fminf(mp, __shfl_xor(mp, 8));
                if ((lane & 15) == 0)
                    atomicMin(&mrun[rf * 16 + (lane >> 4) * 4 + i], __float_as_uint(mp));
            }
#pragma unroll
        for (int cf = 0; cf < 4; ++cf) {
            float mc = acc[0][cf][0];
#pragma unroll
            for (int rf = 0; rf < 4; ++rf)
#pragma unroll
                for (int i = 0; i < 4; ++i) mc = fminf(mc, acc[rf][cf][i]);
            mc = fminf(mc, __shfl_xor(mc, 16));
            mc = fminf(mc, __shfl_xor(mc, 32));
            if (lane < 16) mcode[t * 256 + w * 64 + cf * 16 + lane] = mc;
        }
        __syncthreads();   // mrun now includes this tile

        // epilogue B: margin-collect candidates (superset of fp32 argmin, EPS >= 2*bf16err)
#pragma unroll
        for (int rf = 0; rf < 4; ++rf)
#pragma unroll
            for (int i = 0; i < 4; ++i) {
                unsigned row = rf * 16 + (lane >> 4) * 4 + i;
                float thr = __uint_as_float(mrun[row]) + EPS;
#pragma unroll
                for (int cf = 0; cf < 4; ++cf)
                    if (acc[rf][cf][i] <= thr) {
                        unsigned idx = atomicAdd(&qcount, 1u);
                        unsigned code = t * 256 + w * 64 + cf * 16 + (lane & 15);
                        if (idx < QCAP) queue[idx] = (row << 10) | code;
                    }
            }
    }
    __syncthreads();

    // exact fp32 rescore of candidates (identical formula/association to round-1)
    unsigned qc = qcount; if (qc > QCAP) qc = QCAP;
    for (unsigned q = tid; q < qc; q += 256) {
        unsigned e = queue[q];
        int pl = e >> 10, c = e & 1023;
        const float* xr = x + (size_t)(p0 + pl) * 64;
        const float* cr = cb + c * 64;
        float s = 0.f;
#pragma unroll
        for (int d = 0; d < 64; ++d) s = fmaf(xr[d], cr[d], s);
        float dist = (x2s[pl] - 2.f * s) + c2s[c];
        u64t pk = ((u64t)__float_as_uint(dist) << 32) | (unsigned)c;
        atomicMin(&best[pl], pk);
    }
    __syncthreads();

    if (tid < 64) {
        u64t b = best[tid];
        int k = (int)(b & 0xFFFFFFFFu);
        token[p0 + tid] = k;
        atomicAdd(&active[k], 1);
        dsum[tid] = __uint_as_float((unsigned)(b >> 32));
    }
    __syncthreads();
    if (tid == 0) {
        float s = 0.f;
        for (int i = 0; i < 64; ++i) s += dsum[i];
        lossPartial[blockIdx.x] = s;
    }
    // per-code min -> shard (16-way spread to limit atomic contention)
    {
        unsigned sh = (blockIdx.x & (NSHARD - 1)) * 1024;
#pragma unroll
        for (int q = 0; q < 4; ++q) {
            int c = tid + q * 256;
            atomicMin(&shard[sh + c], __float_as_uint(mcode[c]));
        }
    }
}

// straight-through output
__global__ __launch_bounds__(256) void vq_k2(const float* __restrict__ x,
                                             const float* __restrict__ cb,
                                             const int* __restrict__ token,
                                             float* __restrict__ out) {
    int g = blockIdx.x * 256 + threadIdx.x;
    int p = g >> 4, q = g & 15;
    int tok = token[p];
    float4 xv = reinterpret_cast<const float4*>(x)[g];
    float4 cv = reinterpret_cast<const float4*>(cb)[tok * 16 + q];
    float4 o;
    o.x = xv.x + (cv.x - xv.x);
    o.y = xv.y + (cv.y - xv.y);
    o.z = xv.z + (cv.z - xv.z);
    o.w = xv.w + (cv.w - xv.w);
    reinterpret_cast<float4*>(out)[g] = o;
}

__global__ __launch_bounds__(256) void vq_k3a(const unsigned* __restrict__ shard,
                                              unsigned* __restrict__ minDist) {
    int c = blockIdx.x * 256 + threadIdx.x;   // grid 4
    unsigned m = 0x7F800000u;
#pragma unroll
    for (int s = 0; s < NSHARD; ++s) m = min(m, shard[s * 1024 + c]);
    minDist[c] = m;
}

__global__ __launch_bounds__(1024) void vq_k3(const unsigned* __restrict__ minDist,
                                              const int* __restrict__ active,
                                              const float* __restrict__ lossPartial,
                                              float* __restrict__ out_loss) {
    __shared__ double red[1024];
    __shared__ double entS;
    int t = threadIdx.x;

    red[t] = (active[t] == 0) ? (double)__uint_as_float(minDist[t]) : 0.0;
    __syncthreads();
    for (int s = 512; s > 0; s >>= 1) {
        if (t < s) red[t] += red[t + s];
        __syncthreads();
    }
    if (t == 0) entS = red[0];
    __syncthreads();

    red[t] = (t < 512) ? (double)lossPartial[t] : 0.0;
    __syncthreads();
    for (int s = 512; s > 0; s >>= 1) {
        if (t < s) red[t] += red[t + s];
        __syncthreads();
    }
    if (t == 0) {
        double mean_sq = red[0] / (double)((long long)N_PTS * D_DIM);
        double total = 1.25 * mean_sq + 0.01 * (entS / (double)K_CB);
        out_loss[0] = (float)total;
    }
}

extern "C" void kernel_launch(void* const* d_in, const int* in_sizes, int n_in,
                              void* d_out, int out_size, void* d_ws, size_t ws_size,
                              hipStream_t stream) {
    const float* x  = (const float*)d_in[0];
    const float* cb = (const float*)d_in[1];
    float* out = (float*)d_out;
    char* ws = (char*)d_ws;

    int*            token       = (int*)(ws + WS_TOKEN);
    float*          lossPartial = (float*)(ws + WS_LOSSP);
    unsigned*       minDist     = (unsigned*)(ws + WS_MIND);
    int*            active      = (int*)(ws + WS_ACT);
    float*          c2          = (float*)(ws + WS_C2);
    unsigned short* pcb         = (unsigned short*)(ws + WS_PCB);
    unsigned*       shard       = (unsigned*)(ws + WS_SHARD);

    vq_k0 <<<64,   256, 0, stream>>>(cb, shard, active, c2, pcb);
    vq_k1 <<<512,  256, 0, stream>>>(x, cb, c2, pcb, shard, active, token, lossPartial);
    vq_k2 <<<2048, 256, 0, stream>>>(x, cb, token, out);
    vq_k3a<<<4,    256, 0, stream>>>(shard, minDist);
    vq_k3 <<<1,   1024, 0, stream>>>(minDist, active, lossPartial, out + 2097152);
}